// Round 8
// baseline (214.851 us; speedup 1.0000x reference)
//
#include <hip/hip_runtime.h>
#include <math.h>

// DisCo (distance correlation) for N=8192, scalar output. R8 = R5 structure
// (best-known algebra, absmax 0.0) + MEASUREMENT INSTRUMENTATION: the two pass
// kernels run with gridDim.z = REP identical replicas. Every replica computes
// and stores IDENTICAL values to the SAME addresses (race-free: concurrent
// stores of identical bit patterns; downstream kernels only read after the
// dispatch completes). This makes the pass kernels ~REP x their true duration
// so they surface in rocprof's top-5 WITH counters. True per-pass time =
// dispatch_dur / REP. Next round drops REP to 1 and acts on the evidence.
//   K1 k_pass1 (512x4xREP): partial row sums P0a=Σw|da|, P0b per segment;
//                           per-block double partial for grand means.
//   K2 k_mid   (32):  ga/gb; avg, r=avg-ga/2, s; wr=w*r, ws=w*s; 10 moments.
//   K3 k_pass2 (512x4xREP): 5 pairwise sums/row (8 VALU/pair).
//   K4 k_tail  (32):  per-row T_AB/T_AA/T_BB from partials+moments (double).
//   K5 k_fin   (1x64): final reduce, power branch, NaN/clamp.
// No atomics/fences (R4 lesson). All reductions fixed-order -> deterministic.

#define NN 8192
#define BLK 256
#define RPT 4
#define ROWS_PER_BLOCK 16
#define GRIDX 512
#define CSPLIT 4
#define SEGC 2048
#define ITERS 8
#define NBLK (GRIDX * CSPLIT)
#define MIDB 32
#define INV_N (1.0f / NN)
#define REP 8                           // measurement replication factor

// ---------------------------------------------------------------- K1: pass 1
__device__ __forceinline__ void p1_elem(
    float aj, float bj, float wj,
    const float* __restrict__ ai, const float* __restrict__ bi,
    float* __restrict__ sa, float* __restrict__ sb) {
#pragma unroll
  for (int m = 0; m < RPT; ++m) {
    sa[m] = fmaf(fabsf(ai[m] - aj), wj, sa[m]);
    sb[m] = fmaf(fabsf(bi[m] - bj), wj, sb[m]);
  }
}

__global__ __launch_bounds__(BLK) void k_pass1(
    const float* __restrict__ a, const float* __restrict__ b,
    const float* __restrict__ w,
    float* __restrict__ pa, float* __restrict__ pb,
    double* __restrict__ gpa, double* __restrict__ gpb) {
  const int lane = threadIdx.x & 63;
  const int wv = threadIdx.x >> 6;
  const int i0 = blockIdx.x * ROWS_PER_BLOCK + wv * RPT;
  const int seg = blockIdx.y;

  float ai[RPT], bi[RPT], sa[RPT], sb[RPT];
#pragma unroll
  for (int m = 0; m < RPT; ++m) {
    ai[m] = a[i0 + m]; bi[m] = b[i0 + m];
    sa[m] = 0.f; sb[m] = 0.f;
  }

  const int jb = seg * SEGC;
  const float4* a4 = (const float4*)(a + jb) + lane;
  const float4* b4 = (const float4*)(b + jb) + lane;
  const float4* w4 = (const float4*)(w + jb) + lane;

  float4 A0 = a4[0], B0 = b4[0], W0 = w4[0];
#pragma unroll 1
  for (int k = 0; k < ITERS - 1; ++k) {
    const int nx = (k + 1) * 64;
    const float4 A1 = a4[nx], B1 = b4[nx], W1 = w4[nx];
    p1_elem(A0.x, B0.x, W0.x, ai, bi, sa, sb);
    p1_elem(A0.y, B0.y, W0.y, ai, bi, sa, sb);
    p1_elem(A0.z, B0.z, W0.z, ai, bi, sa, sb);
    p1_elem(A0.w, B0.w, W0.w, ai, bi, sa, sb);
    A0 = A1; B0 = B1; W0 = W1;
  }
  p1_elem(A0.x, B0.x, W0.x, ai, bi, sa, sb);
  p1_elem(A0.y, B0.y, W0.y, ai, bi, sa, sb);
  p1_elem(A0.z, B0.z, W0.z, ai, bi, sa, sb);
  p1_elem(A0.w, B0.w, W0.w, ai, bi, sa, sb);

#pragma unroll
  for (int off = 32; off >= 1; off >>= 1) {
#pragma unroll
    for (int m = 0; m < RPT; ++m) {
      sa[m] += __shfl_xor(sa[m], off);
      sb[m] += __shfl_xor(sb[m], off);
    }
  }

  __shared__ double gla[4], glb[4];
  if (lane == 0) {
#pragma unroll
    for (int m = 0; m < RPT; ++m) {
      pa[seg * NN + i0 + m] = sa[m];
      pb[seg * NN + i0 + m] = sb[m];
    }
    double da = 0.0, db = 0.0;
#pragma unroll
    for (int m = 0; m < RPT; ++m) {
      const double wi = (double)w[i0 + m];
      da += (double)sa[m] * wi;
      db += (double)sb[m] * wi;
    }
    gla[wv] = da; glb[wv] = db;
  }
  __syncthreads();
  if (threadIdx.x == 0) {
    const int bid = blockIdx.y * GRIDX + blockIdx.x;
    gpa[bid] = gla[0] + gla[1] + gla[2] + gla[3];
    gpb[bid] = glb[0] + glb[1] + glb[2] + glb[3];
  }
}

// ------------------------------------- K2: ga/gb, r/s/wr/ws arrays, scalars
__global__ __launch_bounds__(BLK) void k_mid(
    const float* __restrict__ a, const float* __restrict__ b,
    const float* __restrict__ w,
    const float* __restrict__ pa, const float* __restrict__ pb,
    const double* __restrict__ gpa, const double* __restrict__ gpb,
    float* __restrict__ avga, float* __restrict__ avgb,
    float* __restrict__ rr, float* __restrict__ ss,
    float* __restrict__ wr, float* __restrict__ ws,
    double* __restrict__ scal) {
  const int lane = threadIdx.x & 63;
  const int wv = threadIdx.x >> 6;

  __shared__ double gsum[2];
  if (wv < 2) {
    const double* g = wv ? gpb : gpa;
    double s = 0.0;
    for (int k = 0; k < NBLK / 64; ++k) s += g[lane + 64 * k];
#pragma unroll
    for (int off = 32; off >= 1; off >>= 1) s += __shfl_xor(s, off);
    if (lane == 0) gsum[wv] = s;
  }
  __syncthreads();
  const float ha = (float)(0.5 * gsum[0] / ((double)NN * (double)NN));
  const float hb = (float)(0.5 * gsum[1] / ((double)NN * (double)NN));

  const int i = blockIdx.x * BLK + threadIdx.x;
  const float av = (pa[i] + pa[NN + i] + pa[2 * NN + i] + pa[3 * NN + i]) * INV_N;
  const float bv = (pb[i] + pb[NN + i] + pb[2 * NN + i] + pb[3 * NN + i]) * INV_N;
  const float ri = av - ha;
  const float si = bv - hb;
  const float wi = w[i], aiv = a[i], biv = b[i];
  avga[i] = av; avgb[i] = bv;
  rr[i] = ri;  ss[i] = si;
  wr[i] = wi * ri; ws[i] = wi * si;

  double p[10];
  p[0] = (double)wi;
  p[1] = (double)wi * aiv;
  p[2] = (double)wi * aiv * aiv;
  p[3] = (double)wi * biv;
  p[4] = (double)wi * biv * biv;
  p[5] = (double)wi * ri;
  p[6] = (double)wi * si;
  p[7] = (double)wi * ri * ri;
  p[8] = (double)wi * si * si;
  p[9] = (double)wi * ri * si;
#pragma unroll
  for (int off = 32; off >= 1; off >>= 1) {
#pragma unroll
    for (int t = 0; t < 10; ++t) p[t] += __shfl_xor(p[t], off);
  }
  __shared__ double lp[10][4];
  if (lane == 0) {
#pragma unroll
    for (int t = 0; t < 10; ++t) lp[t][wv] = p[t];
  }
  __syncthreads();
  if (threadIdx.x == 0) {
#pragma unroll
    for (int t = 0; t < 10; ++t)
      scal[t * MIDB + blockIdx.x] = lp[t][0] + lp[t][1] + lp[t][2] + lp[t][3];
  }
}

// --------------------------- K3: pass 2 — five pairwise sums, 8 VALU per pair
__global__ __launch_bounds__(BLK) void k_pass2(
    const float* __restrict__ a, const float* __restrict__ b,
    const float* __restrict__ w,
    const float* __restrict__ wr, const float* __restrict__ ws,
    float* __restrict__ Qp, float* __restrict__ P1a, float* __restrict__ P2,
    float* __restrict__ P3, float* __restrict__ P1b) {
  const int lane = threadIdx.x & 63;
  const int wv = threadIdx.x >> 6;
  const int i0 = blockIdx.x * ROWS_PER_BLOCK + wv * RPT;
  const int seg = blockIdx.y;

  float ai[RPT], bi[RPT];
  float q[RPT], g1a[RPT], g2[RPT], g3[RPT], g1b[RPT];
#pragma unroll
  for (int m = 0; m < RPT; ++m) {
    ai[m] = a[i0 + m]; bi[m] = b[i0 + m];
    q[m] = 0.f; g1a[m] = 0.f; g2[m] = 0.f; g3[m] = 0.f; g1b[m] = 0.f;
  }

  const int jb = seg * SEGC;
  const float4* a4 = (const float4*)(a + jb)  + lane;
  const float4* b4 = (const float4*)(b + jb)  + lane;
  const float4* w4 = (const float4*)(w + jb)  + lane;
  const float4* r4 = (const float4*)(wr + jb) + lane;
  const float4* s4 = (const float4*)(ws + jb) + lane;

#pragma unroll 1
  for (int k = 0; k < ITERS; ++k) {
    const int ix = k * 64;
    const float4 A = a4[ix], B = b4[ix], Wt = w4[ix], R = r4[ix], S = s4[ix];
#define P2E(e)                                            \
    {                                                     \
      _Pragma("unroll")                                   \
      for (int m = 0; m < RPT; ++m) {                     \
        const float dd = fabsf(ai[m] - A.e);              \
        const float ee = fabsf(bi[m] - B.e);              \
        g1a[m] = fmaf(R.e, dd, g1a[m]);                   \
        g2[m]  = fmaf(S.e, dd, g2[m]);                    \
        g3[m]  = fmaf(R.e, ee, g3[m]);                    \
        g1b[m] = fmaf(S.e, ee, g1b[m]);                   \
        q[m]   = fmaf(Wt.e * dd, ee, q[m]);               \
      }                                                   \
    }
    P2E(x) P2E(y) P2E(z) P2E(w)
#undef P2E
  }

#pragma unroll
  for (int off = 32; off >= 1; off >>= 1) {
#pragma unroll
    for (int m = 0; m < RPT; ++m) {
      q[m]   += __shfl_xor(q[m], off);
      g1a[m] += __shfl_xor(g1a[m], off);
      g2[m]  += __shfl_xor(g2[m], off);
      g3[m]  += __shfl_xor(g3[m], off);
      g1b[m] += __shfl_xor(g1b[m], off);
    }
  }
  if (lane == 0) {
#pragma unroll
    for (int m = 0; m < RPT; ++m) {
      const int o = seg * NN + i0 + m;
      Qp[o] = q[m]; P1a[o] = g1a[m]; P2[o] = g2[m];
      P3[o] = g3[m]; P1b[o] = g1b[m];
    }
  }
}

// --------------- K4: per-row T_AB/T_AA/T_BB assembly + per-block dbl partials
__global__ __launch_bounds__(BLK) void k_tail(
    const float* __restrict__ a, const float* __restrict__ b,
    const float* __restrict__ w,
    const float* __restrict__ avga, const float* __restrict__ avgb,
    const float* __restrict__ rr, const float* __restrict__ ss,
    const float* __restrict__ Qp, const float* __restrict__ P1a,
    const float* __restrict__ P2, const float* __restrict__ P3,
    const float* __restrict__ P1b,
    const double* __restrict__ scal,
    double* __restrict__ fAB, double* __restrict__ fAA, double* __restrict__ fBB) {
  const int lane = threadIdx.x & 63;
  const int wv = threadIdx.x >> 6;

  __shared__ double sc[10];
  if (threadIdx.x < 10) {
    double s = 0.0;
    for (int k = 0; k < MIDB; ++k) s += scal[threadIdx.x * MIDB + k];
    sc[threadIdx.x] = s;
  }
  __syncthreads();
  const double W   = sc[0], Ma1 = sc[1], Ma2 = sc[2], Mb1 = sc[3], Mb2 = sc[4];
  const double Swr = sc[5], Sws = sc[6], Swr2 = sc[7], Sws2 = sc[8], Swrs = sc[9];

  const int i = blockIdx.x * BLK + threadIdx.x;
  const double Qi   = (double)Qp[i]  + Qp[NN + i]  + Qp[2 * NN + i]  + Qp[3 * NN + i];
  const double P1ai = (double)P1a[i] + P1a[NN + i] + P1a[2 * NN + i] + P1a[3 * NN + i];
  const double P2i  = (double)P2[i]  + P2[NN + i]  + P2[2 * NN + i]  + P2[3 * NN + i];
  const double P3i  = (double)P3[i]  + P3[NN + i]  + P3[2 * NN + i]  + P3[3 * NN + i];
  const double P1bi = (double)P1b[i] + P1b[NN + i] + P1b[2 * NN + i] + P1b[3 * NN + i];
  const double av = avga[i], bv = avgb[i], ri = rr[i], si = ss[i];
  const double aiv = a[i], biv = b[i], wi = w[i];
  const double P0a = av * (double)NN;
  const double P0b = bv * (double)NN;

  const double TAB = Qi - si * P0a - P2i - ri * P0b - P3i
                   + ri * si * W + ri * Sws + si * Swr + Swrs;
  const double TAA = (aiv * aiv * W - 2.0 * aiv * Ma1 + Ma2)
                   - 2.0 * ri * P0a - 2.0 * P1ai
                   + ri * ri * W + 2.0 * ri * Swr + Swr2;
  const double TBB = (biv * biv * W - 2.0 * biv * Mb1 + Mb2)
                   - 2.0 * si * P0b - 2.0 * P1bi
                   + si * si * W + 2.0 * si * Sws + Sws2;

  double ab = fabs(TAB) * wi;
  double aa = TAA * wi;
  double bb = TBB * wi;
#pragma unroll
  for (int off = 32; off >= 1; off >>= 1) {
    ab += __shfl_xor(ab, off);
    aa += __shfl_xor(aa, off);
    bb += __shfl_xor(bb, off);
  }
  __shared__ double l[3][4];
  if (lane == 0) { l[0][wv] = ab; l[1][wv] = aa; l[2][wv] = bb; }
  __syncthreads();
  if (threadIdx.x == 0) {
    fAB[blockIdx.x] = l[0][0] + l[0][1] + l[0][2] + l[0][3];
    fAA[blockIdx.x] = l[1][0] + l[1][1] + l[1][2] + l[1][3];
    fBB[blockIdx.x] = l[2][0] + l[2][1] + l[2][2] + l[2][3];
  }
}

// ---------------------------------------------------------------- K5: finalize
__global__ __launch_bounds__(64) void k_fin(
    const double* __restrict__ fAB, const double* __restrict__ fAA,
    const double* __restrict__ fBB, const int* __restrict__ powerPtr,
    float* __restrict__ out) {
  const int lane = threadIdx.x;
  double ab = fAB[lane & (MIDB - 1)];
  double aa = fAA[lane & (MIDB - 1)];
  double bb = fBB[lane & (MIDB - 1)];
#pragma unroll
  for (int off = 16; off >= 1; off >>= 1) {
    ab += __shfl_xor(ab, off);
    aa += __shfl_xor(aa, off);
    bb += __shfl_xor(bb, off);
  }
  if (lane == 0) {
    const double n2 = (double)NN * (double)NN;
    const double num = ab / n2;
    const double mAA = aa / n2;
    const double mBB = bb / n2;
    const double den = fabs(mAA * mBB);
    const int p = powerPtr[0];
    double d;
    if (p == 1) {
      d = num / sqrt(den + 1e-12);
    } else if (p == 2) {
      d = (num * num) / (den + 1e-12);
    } else {
      d = pow(num / sqrt(mAA * mBB) + 1e-12, (double)p);
    }
    if (isnan(d)) d = 0.0;
    if (d < 0.0) d = 0.0;
    out[0] = (float)d;
  }
}

// -------------------------------------------------------------------- launcher
extern "C" void kernel_launch(void* const* d_in, const int* in_sizes, int n_in,
                              void* d_out, int out_size, void* d_ws, size_t ws_size,
                              hipStream_t stream) {
  const float* a = (const float*)d_in[0];
  const float* b = (const float*)d_in[1];
  const float* w = (const float*)d_in[2];
  const int* power = (const int*)d_in[3];
  float* out = (float*)d_out;

  float* ws = (float*)d_ws;
  float* pa   = ws;                  // [4N]
  float* pb   = pa  + 4 * NN;        // [4N]
  float* Qp   = pb  + 4 * NN;        // [4N]
  float* P1a  = Qp  + 4 * NN;        // [4N]
  float* P2   = P1a + 4 * NN;        // [4N]
  float* P3   = P2  + 4 * NN;        // [4N]
  float* P1b  = P3  + 4 * NN;        // [4N]
  float* avga = P1b + 4 * NN;        // [N]
  float* avgb = avga + NN;           // [N]
  float* rr   = avgb + NN;           // [N]
  float* ss   = rr + NN;             // [N]
  float* wrv  = ss + NN;             // [N]
  float* wsv  = wrv + NN;            // [N]
  double* gpa  = (double*)(wsv + NN);   // [2048]
  double* gpb  = gpa + NBLK;            // [2048]
  double* scal = gpb + NBLK;            // [10*32]
  double* fAB  = scal + 10 * MIDB;      // [32]
  double* fAA  = fAB + MIDB;            // [32]
  double* fBB  = fAA + MIDB;            // [32]

  // gridDim.z = REP identical replicas (measurement): all write same values.
  const dim3 grid(GRIDX, CSPLIT, REP);
  k_pass1<<<grid, BLK, 0, stream>>>(a, b, w, pa, pb, gpa, gpb);
  k_mid<<<MIDB, BLK, 0, stream>>>(a, b, w, pa, pb, gpa, gpb,
                                  avga, avgb, rr, ss, wrv, wsv, scal);
  k_pass2<<<grid, BLK, 0, stream>>>(a, b, w, wrv, wsv, Qp, P1a, P2, P3, P1b);
  k_tail<<<MIDB, BLK, 0, stream>>>(a, b, w, avga, avgb, rr, ss,
                                   Qp, P1a, P2, P3, P1b, scal, fAB, fAA, fBB);
  k_fin<<<1, 64, 0, stream>>>(fAB, fAA, fBB, power, out);
}

// Round 9
// 56.281 us; speedup vs baseline: 3.8174x; 3.8174x over previous
//
#include <hip/hip_runtime.h>
#include <math.h>

// DisCo (distance correlation) for N=8192, scalar output. THREE kernels.
// R8 measurement: pass2 true ~17.3us @ VALUBusy 86% (near VALU limit for its
// stream); pass1 < 5us; ~22us of the 45.5us total was glue kernels + 4 gaps.
// R9 removes the glue algebraically: pass2 sweeps ha-FREE streams
// u=w*avga, v=w*avgb (no grand-mean dependency -> no k_mid), and the ha
// corrections are O(1) per row in the tail:
//   P1a_i = G1a_i - ha*N*avga_i   (wr_j = u_j - ha*w_j)
//   P2_i  = G2_i  - hb*N*avga_i
//   P3_i  = G3_i  - ha*N*avgb_i
//   P1b_i = G1b_i - hb*N*avgb_i
//   K1 k_pass1 (1024x512t): 8 rows/block, 8 waves x 1024-col segments,
//       LDS combine -> FULL row sums; writes avga,avgb,u,v + per-block
//       double partials gpa/gpb (for grand means).
//   K2 k_pass2 (512x4 x256t): R5's measured loop, streams a,b,w,u,v ->
//       per-seg partials Q,G1a,G2,G3,G1b [4][N]  (8 VALU/pair).
//   K3 k_tail  (1x1024): ha/hb; 10 moments; per-row T assembly; final
//       reduce + power branch + NaN/clamp.
// No atomics/fences (R4 lesson). All reductions fixed-order -> deterministic.

#define NN 8192

// ---- K1 geometry
#define BLK1 512
#define NW1 8                    // waves per block
#define RPT1 8                   // rows per block (full rows)
#define GRID1 (NN / RPT1)        // 1024 blocks
#define SEG1 (NN / NW1)          // 1024 cols per wave
#define IT1 (SEG1 / 256)         // 4 float4-rounds per lane

// ---- K2 geometry (R5-identical)
#define BLK 256
#define RPT 4
#define ROWS_PER_BLOCK 16
#define GRIDX 512
#define CSPLIT 4
#define SEGC 2048
#define ITERS 8

#define BLKF 1024

// -------------------------------------------- K1: pass 1, full rows per block
__global__ __launch_bounds__(BLK1) void k_pass1(
    const float* __restrict__ a, const float* __restrict__ b,
    const float* __restrict__ w,
    float* __restrict__ avga, float* __restrict__ avgb,
    float* __restrict__ u, float* __restrict__ v,
    double* __restrict__ gpa, double* __restrict__ gpb) {
  const int lane = threadIdx.x & 63;
  const int wv = threadIdx.x >> 6;
  const int i0 = blockIdx.x * RPT1;

  float ai[RPT1], bi[RPT1], sa[RPT1], sb[RPT1];
#pragma unroll
  for (int m = 0; m < RPT1; ++m) {
    ai[m] = a[i0 + m]; bi[m] = b[i0 + m];
    sa[m] = 0.f; sb[m] = 0.f;
  }

  const int jb = wv * SEG1;
  const float4* a4 = (const float4*)(a + jb) + lane;
  const float4* b4 = (const float4*)(b + jb) + lane;
  const float4* w4 = (const float4*)(w + jb) + lane;

#pragma unroll 1
  for (int k = 0; k < IT1; ++k) {
    const int ix = k * 64;
    const float4 A = a4[ix], B = b4[ix], Wt = w4[ix];
#define P1E(e)                                              \
    {                                                       \
      _Pragma("unroll")                                     \
      for (int m = 0; m < RPT1; ++m) {                      \
        sa[m] = fmaf(fabsf(ai[m] - A.e), Wt.e, sa[m]);      \
        sb[m] = fmaf(fabsf(bi[m] - B.e), Wt.e, sb[m]);      \
      }                                                     \
    }
    P1E(x) P1E(y) P1E(z) P1E(w)
#undef P1E
  }

#pragma unroll
  for (int off = 32; off >= 1; off >>= 1) {
#pragma unroll
    for (int m = 0; m < RPT1; ++m) {
      sa[m] += __shfl_xor(sa[m], off);
      sb[m] += __shfl_xor(sb[m], off);
    }
  }

  __shared__ float lsa[NW1][RPT1], lsb[NW1][RPT1];
  __shared__ float rsA[RPT1], rsB[RPT1];
  if (lane == 0) {
#pragma unroll
    for (int m = 0; m < RPT1; ++m) { lsa[wv][m] = sa[m]; lsb[wv][m] = sb[m]; }
  }
  __syncthreads();
  if (threadIdx.x < RPT1) {
    const int m = threadIdx.x;
    float ra = 0.f, rb = 0.f;
#pragma unroll
    for (int t = 0; t < NW1; ++t) { ra += lsa[t][m]; rb += lsb[t][m]; }
    rsA[m] = ra; rsB[m] = rb;
    const float avA = ra * (1.0f / NN);
    const float avB = rb * (1.0f / NN);
    const float wi = w[i0 + m];
    avga[i0 + m] = avA; avgb[i0 + m] = avB;
    u[i0 + m] = wi * avA;   // ha-free centered-stream pieces
    v[i0 + m] = wi * avB;
  }
  __syncthreads();
  if (threadIdx.x == 0) {
    double da = 0.0, db = 0.0;
#pragma unroll
    for (int m = 0; m < RPT1; ++m) {
      const double wi = (double)w[i0 + m];
      da += wi * (double)rsA[m];
      db += wi * (double)rsB[m];
    }
    gpa[blockIdx.x] = da;
    gpb[blockIdx.x] = db;
  }
}

// --------------------- K2: pass 2 — five pairwise sums with ha-free streams
__global__ __launch_bounds__(BLK) void k_pass2(
    const float* __restrict__ a, const float* __restrict__ b,
    const float* __restrict__ w,
    const float* __restrict__ u, const float* __restrict__ v,
    float* __restrict__ Qp, float* __restrict__ G1a, float* __restrict__ G2,
    float* __restrict__ G3, float* __restrict__ G1b) {
  const int lane = threadIdx.x & 63;
  const int wv = threadIdx.x >> 6;
  const int i0 = blockIdx.x * ROWS_PER_BLOCK + wv * RPT;
  const int seg = blockIdx.y;

  float ai[RPT], bi[RPT];
  float q[RPT], g1a[RPT], g2[RPT], g3[RPT], g1b[RPT];
#pragma unroll
  for (int m = 0; m < RPT; ++m) {
    ai[m] = a[i0 + m]; bi[m] = b[i0 + m];
    q[m] = 0.f; g1a[m] = 0.f; g2[m] = 0.f; g3[m] = 0.f; g1b[m] = 0.f;
  }

  const int jb = seg * SEGC;
  const float4* a4 = (const float4*)(a + jb) + lane;
  const float4* b4 = (const float4*)(b + jb) + lane;
  const float4* w4 = (const float4*)(w + jb) + lane;
  const float4* u4 = (const float4*)(u + jb) + lane;
  const float4* v4 = (const float4*)(v + jb) + lane;

#pragma unroll 1
  for (int k = 0; k < ITERS; ++k) {
    const int ix = k * 64;
    const float4 A = a4[ix], B = b4[ix], Wt = w4[ix], U = u4[ix], V = v4[ix];
#define P2E(e)                                            \
    {                                                     \
      _Pragma("unroll")                                   \
      for (int m = 0; m < RPT; ++m) {                     \
        const float dd = fabsf(ai[m] - A.e);              \
        const float ee = fabsf(bi[m] - B.e);              \
        g1a[m] = fmaf(U.e, dd, g1a[m]);                   \
        g2[m]  = fmaf(V.e, dd, g2[m]);                    \
        g3[m]  = fmaf(U.e, ee, g3[m]);                    \
        g1b[m] = fmaf(V.e, ee, g1b[m]);                   \
        q[m]   = fmaf(Wt.e * dd, ee, q[m]);               \
      }                                                   \
    }
    P2E(x) P2E(y) P2E(z) P2E(w)
#undef P2E
  }

#pragma unroll
  for (int off = 32; off >= 1; off >>= 1) {
#pragma unroll
    for (int m = 0; m < RPT; ++m) {
      q[m]   += __shfl_xor(q[m], off);
      g1a[m] += __shfl_xor(g1a[m], off);
      g2[m]  += __shfl_xor(g2[m], off);
      g3[m]  += __shfl_xor(g3[m], off);
      g1b[m] += __shfl_xor(g1b[m], off);
    }
  }
  if (lane == 0) {
#pragma unroll
    for (int m = 0; m < RPT; ++m) {
      const int o = seg * NN + i0 + m;
      Qp[o] = q[m]; G1a[o] = g1a[m]; G2[o] = g2[m];
      G3[o] = g3[m]; G1b[o] = g1b[m];
    }
  }
}

// ----- K3: single block — ha/hb, moments, per-row T assembly, final scalar
__global__ __launch_bounds__(BLKF) void k_tail(
    const float* __restrict__ a, const float* __restrict__ b,
    const float* __restrict__ w,
    const float* __restrict__ avga, const float* __restrict__ avgb,
    const double* __restrict__ gpa, const double* __restrict__ gpb,
    const float* __restrict__ Qp, const float* __restrict__ G1a,
    const float* __restrict__ G2, const float* __restrict__ G3,
    const float* __restrict__ G1b,
    const int* __restrict__ powerPtr, float* __restrict__ out) {
  const int lane = threadIdx.x & 63;
  const int wvf = threadIdx.x >> 6;   // 16 waves
  const double n2 = (double)NN * (double)NN;

  // ---- phase 1: grand means -> ha, hb
  double da = gpa[threadIdx.x];       // GRID1 == BLKF == 1024
  double db = gpb[threadIdx.x];
#pragma unroll
  for (int off = 32; off >= 1; off >>= 1) {
    da += __shfl_xor(da, off);
    db += __shfl_xor(db, off);
  }
  __shared__ double lg[2][16];
  __shared__ float hsh[2];
  if (lane == 0) { lg[0][wvf] = da; lg[1][wvf] = db; }
  __syncthreads();
  if (threadIdx.x == 0) {
    double ga = 0.0, gb = 0.0;
    for (int t = 0; t < 16; ++t) { ga += lg[0][t]; gb += lg[1][t]; }
    hsh[0] = (float)(0.5 * ga / n2);
    hsh[1] = (float)(0.5 * gb / n2);
  }
  __syncthreads();
  const float ha = hsh[0], hb = hsh[1];

  // ---- phase 2: 10 moments
  double p[10];
#pragma unroll
  for (int t = 0; t < 10; ++t) p[t] = 0.0;
  for (int k = 0; k < NN / BLKF; ++k) {
    const int i = threadIdx.x + k * BLKF;
    const double wi = (double)w[i];
    const double aiv = (double)a[i], biv = (double)b[i];
    const double ri = (double)(avga[i] - ha);
    const double si = (double)(avgb[i] - hb);
    p[0] += wi;
    p[1] += wi * aiv;
    p[2] += wi * aiv * aiv;
    p[3] += wi * biv;
    p[4] += wi * biv * biv;
    p[5] += wi * ri;
    p[6] += wi * si;
    p[7] += wi * ri * ri;
    p[8] += wi * si * si;
    p[9] += wi * ri * si;
  }
#pragma unroll
  for (int off = 32; off >= 1; off >>= 1) {
#pragma unroll
    for (int t = 0; t < 10; ++t) p[t] += __shfl_xor(p[t], off);
  }
  __shared__ double lp[10][16];
  __shared__ double sc[10];
  if (lane == 0) {
#pragma unroll
    for (int t = 0; t < 10; ++t) lp[t][wvf] = p[t];
  }
  __syncthreads();
  if (threadIdx.x < 10) {
    double s = 0.0;
    for (int t = 0; t < 16; ++t) s += lp[threadIdx.x][t];
    sc[threadIdx.x] = s;
  }
  __syncthreads();
  const double W   = sc[0], Ma1 = sc[1], Ma2 = sc[2], Mb1 = sc[3], Mb2 = sc[4];
  const double Swr = sc[5], Sws = sc[6], Swr2 = sc[7], Sws2 = sc[8], Swrs = sc[9];

  // ---- phase 3: per-row T assembly (with ha corrections) + weighted reduce
  double ab = 0.0, aa = 0.0, bb = 0.0;
  for (int k = 0; k < NN / BLKF; ++k) {
    const int i = threadIdx.x + k * BLKF;
    const double Qi  = (double)Qp[i]  + Qp[NN + i]  + Qp[2 * NN + i]  + Qp[3 * NN + i];
    const double g1A = (double)G1a[i] + G1a[NN + i] + G1a[2 * NN + i] + G1a[3 * NN + i];
    const double g2v = (double)G2[i]  + G2[NN + i]  + G2[2 * NN + i]  + G2[3 * NN + i];
    const double g3v = (double)G3[i]  + G3[NN + i]  + G3[2 * NN + i]  + G3[3 * NN + i];
    const double g1B = (double)G1b[i] + G1b[NN + i] + G1b[2 * NN + i] + G1b[3 * NN + i];
    const double av = (double)avga[i], bv = (double)avgb[i];
    const double ri = (double)(avga[i] - ha);
    const double si = (double)(avgb[i] - hb);
    const double aiv = (double)a[i], biv = (double)b[i], wi = (double)w[i];
    const double P0a = av * (double)NN;      // Sum_j w_j |a_i - a_j|
    const double P0b = bv * (double)NN;
    const double P1A = g1A - (double)ha * P0a;
    const double P2v = g2v - (double)hb * P0a;
    const double P3v = g3v - (double)ha * P0b;
    const double P1B = g1B - (double)hb * P0b;

    const double TAB = Qi - si * P0a - P2v - ri * P0b - P3v
                     + ri * si * W + ri * Sws + si * Swr + Swrs;
    const double TAA = (aiv * aiv * W - 2.0 * aiv * Ma1 + Ma2)
                     - 2.0 * ri * P0a - 2.0 * P1A
                     + ri * ri * W + 2.0 * ri * Swr + Swr2;
    const double TBB = (biv * biv * W - 2.0 * biv * Mb1 + Mb2)
                     - 2.0 * si * P0b - 2.0 * P1B
                     + si * si * W + 2.0 * si * Sws + Sws2;

    ab += fabs(TAB) * wi;
    aa += TAA * wi;
    bb += TBB * wi;
  }
#pragma unroll
  for (int off = 32; off >= 1; off >>= 1) {
    ab += __shfl_xor(ab, off);
    aa += __shfl_xor(aa, off);
    bb += __shfl_xor(bb, off);
  }
  __shared__ double l3[3][16];
  if (lane == 0) { l3[0][wvf] = ab; l3[1][wvf] = aa; l3[2][wvf] = bb; }
  __syncthreads();
  if (threadIdx.x == 0) {
    double sab = 0.0, saa = 0.0, sbb = 0.0;
    for (int t = 0; t < 16; ++t) { sab += l3[0][t]; saa += l3[1][t]; sbb += l3[2][t]; }
    const double num = sab / n2;
    const double mAA = saa / n2;
    const double mBB = sbb / n2;
    const double den = fabs(mAA * mBB);
    const int pw = powerPtr[0];
    double d;
    if (pw == 1) {
      d = num / sqrt(den + 1e-12);
    } else if (pw == 2) {
      d = (num * num) / (den + 1e-12);
    } else {
      d = pow(num / sqrt(mAA * mBB) + 1e-12, (double)pw);
    }
    if (isnan(d)) d = 0.0;
    if (d < 0.0) d = 0.0;
    out[0] = (float)d;
  }
}

// -------------------------------------------------------------------- launcher
extern "C" void kernel_launch(void* const* d_in, const int* in_sizes, int n_in,
                              void* d_out, int out_size, void* d_ws, size_t ws_size,
                              hipStream_t stream) {
  const float* a = (const float*)d_in[0];
  const float* b = (const float*)d_in[1];
  const float* w = (const float*)d_in[2];
  const int* power = (const int*)d_in[3];
  float* out = (float*)d_out;

  double* dws = (double*)d_ws;          // 8B-aligned base
  double* gpa = dws;                    // [1024]
  double* gpb = gpa + GRID1;            // [1024]
  float* fp   = (float*)(gpb + GRID1);
  float* Qp   = fp;                     // [4N]
  float* G1a  = Qp  + 4 * NN;           // [4N]
  float* G2   = G1a + 4 * NN;           // [4N]
  float* G3   = G2  + 4 * NN;           // [4N]
  float* G1b  = G3  + 4 * NN;           // [4N]
  float* avga = G1b + 4 * NN;           // [N]
  float* avgb = avga + NN;              // [N]
  float* uu   = avgb + NN;              // [N]
  float* vv   = uu + NN;                // [N]

  k_pass1<<<GRID1, BLK1, 0, stream>>>(a, b, w, avga, avgb, uu, vv, gpa, gpb);
  const dim3 g2(GRIDX, CSPLIT);
  k_pass2<<<g2, BLK, 0, stream>>>(a, b, w, uu, vv, Qp, G1a, G2, G3, G1b);
  k_tail<<<1, BLKF, 0, stream>>>(a, b, w, avga, avgb, gpa, gpb,
                                 Qp, G1a, G2, G3, G1b, power, out);
}

// Round 10
// 50.911 us; speedup vs baseline: 4.2201x; 1.1055x over previous
//
#include <hip/hip_runtime.h>
#include <math.h>

// DisCo (distance correlation) for N=8192, scalar output. FOUR dispatches.
// Evidence (R8 REP-instrumentation): pass2 ~17.3us @ VALUBusy 86%; pass1 <5us;
// glue kernels 1-2us each; remaining ~13-16us ~= per-dispatch overhead
// (~2.5-3us x dispatches). R9 lessons: wave epilogue must be << main loop;
// 1-block kernels must read <<100KB.
// R10: drop k_mid — each pass2 block builds U=w*avga, V=w*avgb for its own
// 2048-col segment in LDS from pass1's partials (redundant x512, ~33MB L2,
// cheap). Grand-mean (ha) corrections stay OUT of the sweep via R9's
// validated ha-free algebra; k_tail(32 blocks) computes ha/hb + 10 global
// moments redundantly per block (fixed order -> deterministic) + per-row T
// assembly -> f[32]; k_fin reduces 32.
//   K1 k_pass1 (512x4): R5-exact. Partials pa,pb[4][N]; dbl gpa/gpb[2048].
//   K2 k_pass2 (512x4): LDS prologue U,V; R5 8-op loop (3 global + 2 LDS
//       streams); G-partials Q,G1a,G2,G3,G1b[4][N].
//   K3 k_tail  (32): ha/hb; moments; T_AB/T_AA/T_BB per row -> f*[32].
//   K4 k_fin   (1x64): final reduce + power branch + NaN/clamp.
// No atomics/fences (R4). All reductions fixed-order -> deterministic.

#define NN 8192
#define BLK 256
#define RPT 4
#define ROWS_PER_BLOCK 16
#define GRIDX 512
#define CSPLIT 4
#define SEGC 2048
#define ITERS 8
#define NBLK (GRIDX * CSPLIT)
#define TAILB 32
#define INV_N (1.0f / NN)

// ---------------------------------------------------------------- K1: pass 1
__device__ __forceinline__ void p1_elem(
    float aj, float bj, float wj,
    const float* __restrict__ ai, const float* __restrict__ bi,
    float* __restrict__ sa, float* __restrict__ sb) {
#pragma unroll
  for (int m = 0; m < RPT; ++m) {
    sa[m] = fmaf(fabsf(ai[m] - aj), wj, sa[m]);
    sb[m] = fmaf(fabsf(bi[m] - bj), wj, sb[m]);
  }
}

__global__ __launch_bounds__(BLK) void k_pass1(
    const float* __restrict__ a, const float* __restrict__ b,
    const float* __restrict__ w,
    float* __restrict__ pa, float* __restrict__ pb,
    double* __restrict__ gpa, double* __restrict__ gpb) {
  const int lane = threadIdx.x & 63;
  const int wv = threadIdx.x >> 6;
  const int i0 = blockIdx.x * ROWS_PER_BLOCK + wv * RPT;
  const int seg = blockIdx.y;

  float ai[RPT], bi[RPT], sa[RPT], sb[RPT];
#pragma unroll
  for (int m = 0; m < RPT; ++m) {
    ai[m] = a[i0 + m]; bi[m] = b[i0 + m];
    sa[m] = 0.f; sb[m] = 0.f;
  }

  const int jb = seg * SEGC;
  const float4* a4 = (const float4*)(a + jb) + lane;
  const float4* b4 = (const float4*)(b + jb) + lane;
  const float4* w4 = (const float4*)(w + jb) + lane;

  float4 A0 = a4[0], B0 = b4[0], W0 = w4[0];
#pragma unroll 1
  for (int k = 0; k < ITERS - 1; ++k) {
    const int nx = (k + 1) * 64;
    const float4 A1 = a4[nx], B1 = b4[nx], W1 = w4[nx];
    p1_elem(A0.x, B0.x, W0.x, ai, bi, sa, sb);
    p1_elem(A0.y, B0.y, W0.y, ai, bi, sa, sb);
    p1_elem(A0.z, B0.z, W0.z, ai, bi, sa, sb);
    p1_elem(A0.w, B0.w, W0.w, ai, bi, sa, sb);
    A0 = A1; B0 = B1; W0 = W1;
  }
  p1_elem(A0.x, B0.x, W0.x, ai, bi, sa, sb);
  p1_elem(A0.y, B0.y, W0.y, ai, bi, sa, sb);
  p1_elem(A0.z, B0.z, W0.z, ai, bi, sa, sb);
  p1_elem(A0.w, B0.w, W0.w, ai, bi, sa, sb);

#pragma unroll
  for (int off = 32; off >= 1; off >>= 1) {
#pragma unroll
    for (int m = 0; m < RPT; ++m) {
      sa[m] += __shfl_xor(sa[m], off);
      sb[m] += __shfl_xor(sb[m], off);
    }
  }

  __shared__ double gla[4], glb[4];
  if (lane == 0) {
#pragma unroll
    for (int m = 0; m < RPT; ++m) {
      pa[seg * NN + i0 + m] = sa[m];
      pb[seg * NN + i0 + m] = sb[m];
    }
    double da = 0.0, db = 0.0;
#pragma unroll
    for (int m = 0; m < RPT; ++m) {
      const double wi = (double)w[i0 + m];
      da += (double)sa[m] * wi;
      db += (double)sb[m] * wi;
    }
    gla[wv] = da; glb[wv] = db;
  }
  __syncthreads();
  if (threadIdx.x == 0) {
    const int bid = blockIdx.y * GRIDX + blockIdx.x;
    gpa[bid] = gla[0] + gla[1] + gla[2] + gla[3];
    gpb[bid] = glb[0] + glb[1] + glb[2] + glb[3];
  }
}

// ----------------- K2: pass 2 — LDS U,V prologue + five pairwise sums (8 op)
__global__ __launch_bounds__(BLK) void k_pass2(
    const float* __restrict__ a, const float* __restrict__ b,
    const float* __restrict__ w,
    const float* __restrict__ pa, const float* __restrict__ pb,
    float* __restrict__ Qp, float* __restrict__ G1a, float* __restrict__ G2,
    float* __restrict__ G3, float* __restrict__ G1b) {
  const int lane = threadIdx.x & 63;
  const int wv = threadIdx.x >> 6;
  const int i0 = blockIdx.x * ROWS_PER_BLOCK + wv * RPT;
  const int seg = blockIdx.y;
  const int jb = seg * SEGC;

  // ---- prologue: build U = w*avga, V = w*avgb for this segment's columns
  __shared__ float U[SEGC], V[SEGC];
#pragma unroll
  for (int c = 0; c < SEGC / BLK; ++c) {
    const int j = threadIdx.x + c * BLK;
    const int jj = jb + j;
    const float avA = (pa[jj] + pa[NN + jj] + pa[2 * NN + jj] + pa[3 * NN + jj]) * INV_N;
    const float avB = (pb[jj] + pb[NN + jj] + pb[2 * NN + jj] + pb[3 * NN + jj]) * INV_N;
    const float wj = w[jj];
    U[j] = wj * avA;
    V[j] = wj * avB;
  }
  __syncthreads();

  float ai[RPT], bi[RPT];
  float q[RPT], g1a[RPT], g2[RPT], g3[RPT], g1b[RPT];
#pragma unroll
  for (int m = 0; m < RPT; ++m) {
    ai[m] = a[i0 + m]; bi[m] = b[i0 + m];
    q[m] = 0.f; g1a[m] = 0.f; g2[m] = 0.f; g3[m] = 0.f; g1b[m] = 0.f;
  }

  const float4* a4 = (const float4*)(a + jb) + lane;
  const float4* b4 = (const float4*)(b + jb) + lane;
  const float4* w4 = (const float4*)(w + jb) + lane;
  const float4* U4 = (const float4*)U + lane;
  const float4* V4 = (const float4*)V + lane;

#pragma unroll 1
  for (int k = 0; k < ITERS; ++k) {
    const int ix = k * 64;
    const float4 A = a4[ix], B = b4[ix], Wt = w4[ix];
    const float4 Uv = U4[ix], Vv = V4[ix];
#define P2E(e)                                            \
    {                                                     \
      _Pragma("unroll")                                   \
      for (int m = 0; m < RPT; ++m) {                     \
        const float dd = fabsf(ai[m] - A.e);              \
        const float ee = fabsf(bi[m] - B.e);              \
        g1a[m] = fmaf(Uv.e, dd, g1a[m]);                  \
        g2[m]  = fmaf(Vv.e, dd, g2[m]);                   \
        g3[m]  = fmaf(Uv.e, ee, g3[m]);                   \
        g1b[m] = fmaf(Vv.e, ee, g1b[m]);                  \
        q[m]   = fmaf(Wt.e * dd, ee, q[m]);               \
      }                                                   \
    }
    P2E(x) P2E(y) P2E(z) P2E(w)
#undef P2E
  }

#pragma unroll
  for (int off = 32; off >= 1; off >>= 1) {
#pragma unroll
    for (int m = 0; m < RPT; ++m) {
      q[m]   += __shfl_xor(q[m], off);
      g1a[m] += __shfl_xor(g1a[m], off);
      g2[m]  += __shfl_xor(g2[m], off);
      g3[m]  += __shfl_xor(g3[m], off);
      g1b[m] += __shfl_xor(g1b[m], off);
    }
  }
  if (lane == 0) {
#pragma unroll
    for (int m = 0; m < RPT; ++m) {
      const int o = seg * NN + i0 + m;
      Qp[o] = q[m]; G1a[o] = g1a[m]; G2[o] = g2[m];
      G3[o] = g3[m]; G1b[o] = g1b[m];
    }
  }
}

// -------- K3: ha/hb + global moments (redundant per block) + per-row T + f[32]
__global__ __launch_bounds__(BLK) void k_tail(
    const float* __restrict__ a, const float* __restrict__ b,
    const float* __restrict__ w,
    const float* __restrict__ pa, const float* __restrict__ pb,
    const double* __restrict__ gpa, const double* __restrict__ gpb,
    const float* __restrict__ Qp, const float* __restrict__ G1a,
    const float* __restrict__ G2, const float* __restrict__ G3,
    const float* __restrict__ G1b,
    double* __restrict__ fAB, double* __restrict__ fAA, double* __restrict__ fBB) {
  const int lane = threadIdx.x & 63;
  const int wv = threadIdx.x >> 6;
  const double n2 = (double)NN * (double)NN;

  // ---- phase A: grand means -> ha, hb (identical fixed-order in every block)
  double da = 0.0, db = 0.0;
#pragma unroll
  for (int k = 0; k < NBLK / BLK; ++k) {
    const int t = threadIdx.x + k * BLK;
    da += gpa[t]; db += gpb[t];
  }
#pragma unroll
  for (int off = 32; off >= 1; off >>= 1) {
    da += __shfl_xor(da, off);
    db += __shfl_xor(db, off);
  }
  __shared__ double lg[2][4];
  __shared__ float hsh[2];
  if (lane == 0) { lg[0][wv] = da; lg[1][wv] = db; }
  __syncthreads();
  if (threadIdx.x == 0) {
    const double ga = lg[0][0] + lg[0][1] + lg[0][2] + lg[0][3];
    const double gb = lg[1][0] + lg[1][1] + lg[1][2] + lg[1][3];
    hsh[0] = (float)(0.5 * ga / n2);
    hsh[1] = (float)(0.5 * gb / n2);
  }
  __syncthreads();
  const float ha = hsh[0], hb = hsh[1];

  // ---- phase B: 10 global moments (redundant, fixed-order -> deterministic)
  double p[10];
#pragma unroll
  for (int t = 0; t < 10; ++t) p[t] = 0.0;
  for (int k = 0; k < NN / BLK; ++k) {
    const int i = threadIdx.x + k * BLK;
    const float avA = (pa[i] + pa[NN + i] + pa[2 * NN + i] + pa[3 * NN + i]) * INV_N;
    const float avB = (pb[i] + pb[NN + i] + pb[2 * NN + i] + pb[3 * NN + i]) * INV_N;
    const double wi = (double)w[i];
    const double aiv = (double)a[i], biv = (double)b[i];
    const double ri = (double)(avA - ha);
    const double si = (double)(avB - hb);
    p[0] += wi;
    p[1] += wi * aiv;
    p[2] += wi * aiv * aiv;
    p[3] += wi * biv;
    p[4] += wi * biv * biv;
    p[5] += wi * ri;
    p[6] += wi * si;
    p[7] += wi * ri * ri;
    p[8] += wi * si * si;
    p[9] += wi * ri * si;
  }
#pragma unroll
  for (int off = 32; off >= 1; off >>= 1) {
#pragma unroll
    for (int t = 0; t < 10; ++t) p[t] += __shfl_xor(p[t], off);
  }
  __shared__ double lp[10][4];
  __shared__ double sc[10];
  if (lane == 0) {
#pragma unroll
    for (int t = 0; t < 10; ++t) lp[t][wv] = p[t];
  }
  __syncthreads();
  if (threadIdx.x < 10) {
    sc[threadIdx.x] = lp[threadIdx.x][0] + lp[threadIdx.x][1]
                    + lp[threadIdx.x][2] + lp[threadIdx.x][3];
  }
  __syncthreads();
  const double W   = sc[0], Ma1 = sc[1], Ma2 = sc[2], Mb1 = sc[3], Mb2 = sc[4];
  const double Swr = sc[5], Sws = sc[6], Swr2 = sc[7], Sws2 = sc[8], Swrs = sc[9];

  // ---- phase C: per-row T assembly (256 rows per block) + weighted partials
  const int i = blockIdx.x * BLK + threadIdx.x;
  const double Qi  = (double)Qp[i]  + Qp[NN + i]  + Qp[2 * NN + i]  + Qp[3 * NN + i];
  const double g1A = (double)G1a[i] + G1a[NN + i] + G1a[2 * NN + i] + G1a[3 * NN + i];
  const double g2v = (double)G2[i]  + G2[NN + i]  + G2[2 * NN + i]  + G2[3 * NN + i];
  const double g3v = (double)G3[i]  + G3[NN + i]  + G3[2 * NN + i]  + G3[3 * NN + i];
  const double g1B = (double)G1b[i] + G1b[NN + i] + G1b[2 * NN + i] + G1b[3 * NN + i];
  const float avAf = (pa[i] + pa[NN + i] + pa[2 * NN + i] + pa[3 * NN + i]) * INV_N;
  const float avBf = (pb[i] + pb[NN + i] + pb[2 * NN + i] + pb[3 * NN + i]) * INV_N;
  const double av = (double)avAf, bv = (double)avBf;
  const double ri = (double)(avAf - ha);
  const double si = (double)(avBf - hb);
  const double aiv = (double)a[i], biv = (double)b[i], wi = (double)w[i];
  const double P0a = av * (double)NN;      // Sum_j w_j |a_i - a_j|
  const double P0b = bv * (double)NN;
  const double P1A = g1A - (double)ha * P0a;
  const double P2v = g2v - (double)hb * P0a;
  const double P3v = g3v - (double)ha * P0b;
  const double P1B = g1B - (double)hb * P0b;

  const double TAB = Qi - si * P0a - P2v - ri * P0b - P3v
                   + ri * si * W + ri * Sws + si * Swr + Swrs;
  const double TAA = (aiv * aiv * W - 2.0 * aiv * Ma1 + Ma2)
                   - 2.0 * ri * P0a - 2.0 * P1A
                   + ri * ri * W + 2.0 * ri * Swr + Swr2;
  const double TBB = (biv * biv * W - 2.0 * biv * Mb1 + Mb2)
                   - 2.0 * si * P0b - 2.0 * P1B
                   + si * si * W + 2.0 * si * Sws + Sws2;

  double ab = fabs(TAB) * wi;
  double aa = TAA * wi;
  double bb = TBB * wi;
#pragma unroll
  for (int off = 32; off >= 1; off >>= 1) {
    ab += __shfl_xor(ab, off);
    aa += __shfl_xor(aa, off);
    bb += __shfl_xor(bb, off);
  }
  __shared__ double l3[3][4];
  if (lane == 0) { l3[0][wv] = ab; l3[1][wv] = aa; l3[2][wv] = bb; }
  __syncthreads();
  if (threadIdx.x == 0) {
    fAB[blockIdx.x] = l3[0][0] + l3[0][1] + l3[0][2] + l3[0][3];
    fAA[blockIdx.x] = l3[1][0] + l3[1][1] + l3[1][2] + l3[1][3];
    fBB[blockIdx.x] = l3[2][0] + l3[2][1] + l3[2][2] + l3[2][3];
  }
}

// ---------------------------------------------------------------- K4: finalize
__global__ __launch_bounds__(64) void k_fin(
    const double* __restrict__ fAB, const double* __restrict__ fAA,
    const double* __restrict__ fBB, const int* __restrict__ powerPtr,
    float* __restrict__ out) {
  const int lane = threadIdx.x;
  double ab = fAB[lane & (TAILB - 1)];
  double aa = fAA[lane & (TAILB - 1)];
  double bb = fBB[lane & (TAILB - 1)];
#pragma unroll
  for (int off = 16; off >= 1; off >>= 1) {
    ab += __shfl_xor(ab, off);
    aa += __shfl_xor(aa, off);
    bb += __shfl_xor(bb, off);
  }
  if (lane == 0) {
    const double n2 = (double)NN * (double)NN;
    const double num = ab / n2;
    const double mAA = aa / n2;
    const double mBB = bb / n2;
    const double den = fabs(mAA * mBB);
    const int p = powerPtr[0];
    double d;
    if (p == 1) {
      d = num / sqrt(den + 1e-12);
    } else if (p == 2) {
      d = (num * num) / (den + 1e-12);
    } else {
      d = pow(num / sqrt(mAA * mBB) + 1e-12, (double)p);
    }
    if (isnan(d)) d = 0.0;
    if (d < 0.0) d = 0.0;
    out[0] = (float)d;
  }
}

// -------------------------------------------------------------------- launcher
extern "C" void kernel_launch(void* const* d_in, const int* in_sizes, int n_in,
                              void* d_out, int out_size, void* d_ws, size_t ws_size,
                              hipStream_t stream) {
  const float* a = (const float*)d_in[0];
  const float* b = (const float*)d_in[1];
  const float* w = (const float*)d_in[2];
  const int* power = (const int*)d_in[3];
  float* out = (float*)d_out;

  double* dws = (double*)d_ws;          // 8B-aligned base
  double* gpa = dws;                    // [2048]
  double* gpb = gpa + NBLK;             // [2048]
  double* fAB = gpb + NBLK;             // [32]
  double* fAA = fAB + TAILB;            // [32]
  double* fBB = fAA + TAILB;            // [32]
  float* fp   = (float*)(fBB + TAILB);
  float* pa   = fp;                     // [4N]
  float* pb   = pa  + 4 * NN;           // [4N]
  float* Qp   = pb  + 4 * NN;           // [4N]
  float* G1a  = Qp  + 4 * NN;           // [4N]
  float* G2   = G1a + 4 * NN;           // [4N]
  float* G3   = G2  + 4 * NN;           // [4N]
  float* G1b  = G3  + 4 * NN;           // [4N]

  const dim3 grid(GRIDX, CSPLIT);
  k_pass1<<<grid, BLK, 0, stream>>>(a, b, w, pa, pb, gpa, gpb);
  k_pass2<<<grid, BLK, 0, stream>>>(a, b, w, pa, pb, Qp, G1a, G2, G3, G1b);
  k_tail<<<TAILB, BLK, 0, stream>>>(a, b, w, pa, pb, gpa, gpb,
                                    Qp, G1a, G2, G3, G1b, fAB, fAA, fBB);
  k_fin<<<1, 64, 0, stream>>>(fAB, fAA, fBB, power, out);
}

// Round 11
// 40.149 us; speedup vs baseline: 5.3514x; 1.2681x over previous
//
#include <hip/hip_runtime.h>
#include <math.h>

// DisCo (distance correlation) for N=8192, scalar output. 5 kernels (R5 skeleton).
// R11 algebra: only num needs per-row pairwise data. Denominators are GLOBAL:
//   S_AA = sum_i w_i T_AA_i = 2W*Ma2 - 2*Ma1^2 - 4N*(Swr2 + ha*Swr)
//          + 2W*Swr2 + 2*Swr^2          (all O(N) moments; symmetry closes it)
// and T_AB needs ONE pairwise sum: with d' = |a_i-a_j| - r_j, e' = |b_i-b_j| - s_j,
//   Q'_i = sum_j w_j d' e'  (6 VALU/pair, 1 accumulator/row)
//   T_AB_i = Q'_i - s_i(P0a_i - Swr) - r_i(P0b_i - Sws) + r_i s_i W
// where r = avga - ha (ha = ga/2), P0a_i = N*avga_i.
//   K1 k_pass1 (512x4): R5-exact partial row sums pa,pb + dbl gpa/gpb[2048].
//   K2 k_mid   (32):    ha/hb; rr=avga-ha, ss arrays; 9 moment partials; hs[2].
//   K3 k_pass2 (512x4): Q' only — streams a,b,w,rr,ss; 6 ops/pair; Qp[4][N].
//   K4 k_tail  (32):    per-row T_AB assembly + w|T_AB| -> f[32].
//   K5 k_fin   (1x64):  num; closed-form S_AA/S_BB; power branch; NaN/clamp.
// No atomics/fences (R4). Fixed-order reductions -> deterministic.
// Lessons honored: no per-block redundant O(N) rebuilds (R10), wave epilogue
// << main loop (R9), small VGPR in passes (R6).

#define NN 8192
#define BLK 256
#define RPT 4
#define ROWS_PER_BLOCK 16
#define GRIDX 512
#define CSPLIT 4
#define SEGC 2048
#define ITERS 8
#define NBLK (GRIDX * CSPLIT)
#define MIDB 32
#define INV_N (1.0f / NN)
#define NSC 9   // moments: 0:W 1:Ma1 2:Ma2 3:Mb1 4:Mb2 5:Swr 6:Sws 7:Swr2 8:Sws2

// ---------------------------------------------------------------- K1: pass 1
__device__ __forceinline__ void p1_elem(
    float aj, float bj, float wj,
    const float* __restrict__ ai, const float* __restrict__ bi,
    float* __restrict__ sa, float* __restrict__ sb) {
#pragma unroll
  for (int m = 0; m < RPT; ++m) {
    sa[m] = fmaf(fabsf(ai[m] - aj), wj, sa[m]);
    sb[m] = fmaf(fabsf(bi[m] - bj), wj, sb[m]);
  }
}

__global__ __launch_bounds__(BLK) void k_pass1(
    const float* __restrict__ a, const float* __restrict__ b,
    const float* __restrict__ w,
    float* __restrict__ pa, float* __restrict__ pb,
    double* __restrict__ gpa, double* __restrict__ gpb) {
  const int lane = threadIdx.x & 63;
  const int wv = threadIdx.x >> 6;
  const int i0 = blockIdx.x * ROWS_PER_BLOCK + wv * RPT;
  const int seg = blockIdx.y;

  float ai[RPT], bi[RPT], sa[RPT], sb[RPT];
#pragma unroll
  for (int m = 0; m < RPT; ++m) {
    ai[m] = a[i0 + m]; bi[m] = b[i0 + m];
    sa[m] = 0.f; sb[m] = 0.f;
  }

  const int jb = seg * SEGC;
  const float4* a4 = (const float4*)(a + jb) + lane;
  const float4* b4 = (const float4*)(b + jb) + lane;
  const float4* w4 = (const float4*)(w + jb) + lane;

  float4 A0 = a4[0], B0 = b4[0], W0 = w4[0];
#pragma unroll 1
  for (int k = 0; k < ITERS - 1; ++k) {
    const int nx = (k + 1) * 64;
    const float4 A1 = a4[nx], B1 = b4[nx], W1 = w4[nx];
    p1_elem(A0.x, B0.x, W0.x, ai, bi, sa, sb);
    p1_elem(A0.y, B0.y, W0.y, ai, bi, sa, sb);
    p1_elem(A0.z, B0.z, W0.z, ai, bi, sa, sb);
    p1_elem(A0.w, B0.w, W0.w, ai, bi, sa, sb);
    A0 = A1; B0 = B1; W0 = W1;
  }
  p1_elem(A0.x, B0.x, W0.x, ai, bi, sa, sb);
  p1_elem(A0.y, B0.y, W0.y, ai, bi, sa, sb);
  p1_elem(A0.z, B0.z, W0.z, ai, bi, sa, sb);
  p1_elem(A0.w, B0.w, W0.w, ai, bi, sa, sb);

#pragma unroll
  for (int off = 32; off >= 1; off >>= 1) {
#pragma unroll
    for (int m = 0; m < RPT; ++m) {
      sa[m] += __shfl_xor(sa[m], off);
      sb[m] += __shfl_xor(sb[m], off);
    }
  }

  __shared__ double gla[4], glb[4];
  if (lane == 0) {
#pragma unroll
    for (int m = 0; m < RPT; ++m) {
      pa[seg * NN + i0 + m] = sa[m];
      pb[seg * NN + i0 + m] = sb[m];
    }
    double da = 0.0, db = 0.0;
#pragma unroll
    for (int m = 0; m < RPT; ++m) {
      const double wi = (double)w[i0 + m];
      da += (double)sa[m] * wi;
      db += (double)sb[m] * wi;
    }
    gla[wv] = da; glb[wv] = db;
  }
  __syncthreads();
  if (threadIdx.x == 0) {
    const int bid = blockIdx.y * GRIDX + blockIdx.x;
    gpa[bid] = gla[0] + gla[1] + gla[2] + gla[3];
    gpb[bid] = glb[0] + glb[1] + glb[2] + glb[3];
  }
}

// ---------------- K2: ha/hb; rr/ss arrays; 9 moment partials; hs[2] scalars
__global__ __launch_bounds__(BLK) void k_mid(
    const float* __restrict__ a, const float* __restrict__ b,
    const float* __restrict__ w,
    const float* __restrict__ pa, const float* __restrict__ pb,
    const double* __restrict__ gpa, const double* __restrict__ gpb,
    float* __restrict__ rr, float* __restrict__ ss,
    double* __restrict__ scal, double* __restrict__ hs) {
  const int lane = threadIdx.x & 63;
  const int wv = threadIdx.x >> 6;

  __shared__ double gsum[2];
  if (wv < 2) {                 // wave0 -> ga partials, wave1 -> gb partials
    const double* g = wv ? gpb : gpa;
    double s = 0.0;
    for (int k = 0; k < NBLK / 64; ++k) s += g[lane + 64 * k];
#pragma unroll
    for (int off = 32; off >= 1; off >>= 1) s += __shfl_xor(s, off);
    if (lane == 0) gsum[wv] = s;
  }
  __syncthreads();
  const double n2 = (double)NN * (double)NN;
  const float ha = (float)(0.5 * gsum[0] / n2);   // ga/2
  const float hb = (float)(0.5 * gsum[1] / n2);
  if (blockIdx.x == 0 && threadIdx.x == 0) { hs[0] = (double)ha; hs[1] = (double)hb; }

  const int i = blockIdx.x * BLK + threadIdx.x;   // MIDB*BLK == NN
  const float av = (pa[i] + pa[NN + i] + pa[2 * NN + i] + pa[3 * NN + i]) * INV_N;
  const float bv = (pb[i] + pb[NN + i] + pb[2 * NN + i] + pb[3 * NN + i]) * INV_N;
  const float ri = av - ha;
  const float si = bv - hb;
  const float wi = w[i], aiv = a[i], biv = b[i];
  rr[i] = ri;  ss[i] = si;

  double p[NSC];
  p[0] = (double)wi;
  p[1] = (double)wi * aiv;
  p[2] = (double)wi * aiv * aiv;
  p[3] = (double)wi * biv;
  p[4] = (double)wi * biv * biv;
  p[5] = (double)wi * ri;
  p[6] = (double)wi * si;
  p[7] = (double)wi * ri * ri;
  p[8] = (double)wi * si * si;
#pragma unroll
  for (int off = 32; off >= 1; off >>= 1) {
#pragma unroll
    for (int t = 0; t < NSC; ++t) p[t] += __shfl_xor(p[t], off);
  }
  __shared__ double lp[NSC][4];
  if (lane == 0) {
#pragma unroll
    for (int t = 0; t < NSC; ++t) lp[t][wv] = p[t];
  }
  __syncthreads();
  if (threadIdx.x == 0) {
#pragma unroll
    for (int t = 0; t < NSC; ++t)
      scal[t * MIDB + blockIdx.x] = lp[t][0] + lp[t][1] + lp[t][2] + lp[t][3];
  }
}

// ------------------- K3: pass 2 — single pairwise sum Q', 6 VALU per pair
__global__ __launch_bounds__(BLK) void k_pass2(
    const float* __restrict__ a, const float* __restrict__ b,
    const float* __restrict__ w,
    const float* __restrict__ rr, const float* __restrict__ ss,
    float* __restrict__ Qp) {
  const int lane = threadIdx.x & 63;
  const int wv = threadIdx.x >> 6;
  const int i0 = blockIdx.x * ROWS_PER_BLOCK + wv * RPT;
  const int seg = blockIdx.y;

  float ai[RPT], bi[RPT], q[RPT];
#pragma unroll
  for (int m = 0; m < RPT; ++m) {
    ai[m] = a[i0 + m]; bi[m] = b[i0 + m];
    q[m] = 0.f;
  }

  const int jb = seg * SEGC;
  const float4* a4 = (const float4*)(a + jb)  + lane;
  const float4* b4 = (const float4*)(b + jb)  + lane;
  const float4* w4 = (const float4*)(w + jb)  + lane;
  const float4* r4 = (const float4*)(rr + jb) + lane;
  const float4* s4 = (const float4*)(ss + jb) + lane;

#pragma unroll 1
  for (int k = 0; k < ITERS; ++k) {
    const int ix = k * 64;
    const float4 A = a4[ix], B = b4[ix], Wt = w4[ix], R = r4[ix], S = s4[ix];
#define P2E(e)                                            \
    {                                                     \
      _Pragma("unroll")                                   \
      for (int m = 0; m < RPT; ++m) {                     \
        const float dp = fabsf(ai[m] - A.e) - R.e;        \
        const float ep = fabsf(bi[m] - B.e) - S.e;        \
        q[m] = fmaf(Wt.e * dp, ep, q[m]);                 \
      }                                                   \
    }
    P2E(x) P2E(y) P2E(z) P2E(w)
#undef P2E
  }

#pragma unroll
  for (int off = 32; off >= 1; off >>= 1) {
#pragma unroll
    for (int m = 0; m < RPT; ++m) q[m] += __shfl_xor(q[m], off);
  }
  if (lane == 0) {
#pragma unroll
    for (int m = 0; m < RPT; ++m) Qp[seg * NN + i0 + m] = q[m];
  }
}

// ------------------- K4: per-row T_AB assembly + w|T_AB| -> f[32] partials
__global__ __launch_bounds__(BLK) void k_tail(
    const float* __restrict__ w,
    const float* __restrict__ rr, const float* __restrict__ ss,
    const float* __restrict__ Qp,
    const double* __restrict__ scal, const double* __restrict__ hs,
    double* __restrict__ fAB) {
  const int lane = threadIdx.x & 63;
  const int wv = threadIdx.x >> 6;

  __shared__ double sc3[3];   // W, Swr, Sws
  if (threadIdx.x < 3) {
    const int t = (threadIdx.x == 0) ? 0 : (threadIdx.x == 1) ? 5 : 6;
    double s = 0.0;
    for (int k = 0; k < MIDB; ++k) s += scal[t * MIDB + k];
    sc3[threadIdx.x] = s;
  }
  __syncthreads();
  const double W = sc3[0], Swr = sc3[1], Sws = sc3[2];
  const double ha = hs[0], hb = hs[1];

  const int i = blockIdx.x * BLK + threadIdx.x;
  const double Qi = (double)Qp[i] + Qp[NN + i] + Qp[2 * NN + i] + Qp[3 * NN + i];
  const double ri = (double)rr[i];
  const double si = (double)ss[i];
  const double wi = (double)w[i];
  const double P0a = ((double)rr[i] + ha) * (double)NN;   // N * avga_i
  const double P0b = ((double)ss[i] + hb) * (double)NN;

  const double TAB = Qi - si * (P0a - Swr) - ri * (P0b - Sws) + ri * si * W;

  double ab = fabs(TAB) * wi;
#pragma unroll
  for (int off = 32; off >= 1; off >>= 1) ab += __shfl_xor(ab, off);
  __shared__ double l[4];
  if (lane == 0) l[wv] = ab;
  __syncthreads();
  if (threadIdx.x == 0) fAB[blockIdx.x] = l[0] + l[1] + l[2] + l[3];
}

// ---------- K5: finalize — num; closed-form S_AA/S_BB; power; NaN/clamp
__global__ __launch_bounds__(64) void k_fin(
    const double* __restrict__ fAB, const double* __restrict__ scal,
    const double* __restrict__ hs, const int* __restrict__ powerPtr,
    float* __restrict__ out) {
  const int lane = threadIdx.x;

  double ab = (lane < MIDB) ? fAB[lane] : 0.0;
#pragma unroll
  for (int off = 32; off >= 1; off >>= 1) ab += __shfl_xor(ab, off);

  __shared__ double sc[NSC];
  if (lane < NSC) {
    double s = 0.0;
    for (int k = 0; k < MIDB; ++k) s += scal[lane * MIDB + k];
    sc[lane] = s;
  }
  __syncthreads();

  if (lane == 0) {
    const double n2 = (double)NN * (double)NN;
    const double W = sc[0], Ma1 = sc[1], Ma2 = sc[2], Mb1 = sc[3], Mb2 = sc[4];
    const double Swr = sc[5], Sws = sc[6], Swr2 = sc[7], Sws2 = sc[8];
    const double ha = hs[0], hb = hs[1];

    // S_AA = sum_ij w_i w_j A_ij^2 (global, closed form)
    const double S_AA = 2.0 * W * Ma2 - 2.0 * Ma1 * Ma1
                      - 4.0 * (double)NN * (Swr2 + ha * Swr)
                      + 2.0 * W * Swr2 + 2.0 * Swr * Swr;
    const double S_BB = 2.0 * W * Mb2 - 2.0 * Mb1 * Mb1
                      - 4.0 * (double)NN * (Sws2 + hb * Sws)
                      + 2.0 * W * Sws2 + 2.0 * Sws * Sws;

    const double num = ab / n2;
    const double mAA = S_AA / n2;
    const double mBB = S_BB / n2;
    const double den = fabs(mAA * mBB);
    const int p = powerPtr[0];
    double d;
    if (p == 1) {
      d = num / sqrt(den + 1e-12);
    } else if (p == 2) {
      d = (num * num) / (den + 1e-12);
    } else {
      d = pow(num / sqrt(mAA * mBB) + 1e-12, (double)p);
    }
    if (isnan(d)) d = 0.0;
    if (d < 0.0) d = 0.0;
    out[0] = (float)d;
  }
}

// -------------------------------------------------------------------- launcher
extern "C" void kernel_launch(void* const* d_in, const int* in_sizes, int n_in,
                              void* d_out, int out_size, void* d_ws, size_t ws_size,
                              hipStream_t stream) {
  const float* a = (const float*)d_in[0];
  const float* b = (const float*)d_in[1];
  const float* w = (const float*)d_in[2];
  const int* power = (const int*)d_in[3];
  float* out = (float*)d_out;

  double* dws = (double*)d_ws;           // 8B-aligned base
  double* gpa  = dws;                    // [2048]
  double* gpb  = gpa + NBLK;             // [2048]
  double* scal = gpb + NBLK;             // [9*32]
  double* hs   = scal + NSC * MIDB;      // [2]
  double* fAB  = hs + 2;                 // [32]
  float* fp    = (float*)(fAB + MIDB);
  float* pa    = fp;                     // [4N]
  float* pb    = pa + 4 * NN;            // [4N]
  float* Qp    = pb + 4 * NN;            // [4N]
  float* rr    = Qp + 4 * NN;            // [N]
  float* ss    = rr + NN;                // [N]

  const dim3 grid(GRIDX, CSPLIT);
  k_pass1<<<grid, BLK, 0, stream>>>(a, b, w, pa, pb, gpa, gpb);
  k_mid<<<MIDB, BLK, 0, stream>>>(a, b, w, pa, pb, gpa, gpb, rr, ss, scal, hs);
  k_pass2<<<grid, BLK, 0, stream>>>(a, b, w, rr, ss, Qp);
  k_tail<<<MIDB, BLK, 0, stream>>>(w, rr, ss, Qp, scal, hs, fAB);
  k_fin<<<1, 64, 0, stream>>>(fAB, scal, hs, power, out);
}